// Round 5
// baseline (71.996 us; speedup 1.0000x reference)
//
#include <hip/hip_runtime.h>
#include <cstdint>

// ChamferLoss on MI355X.
//   nn_kernel (x2, roles swapped): per query, group-hierarchical min of
//     e = ||t||^2 - 2 q.t.  x,y via v_dot2_f32_f16 (f32 accumulate), z and
//     ||t||^2 exact fp32:  e = fdot2(t_xy, q_xy, fmaf(t_z, -2qz, w)).
//     TM=4 queries/thread so 3x ds_read_b128 serve 16 pairs (LDS-pipe was
//     the R4 bottleneck); explicit next-subtile register prefetch.
//     Each (tile,chunk) block writes partial keys (monotone(e)<<32 | group)
//     to DISJOINT pkeys slots -> no init memset, no atomics.
//   combine_kernel (x2): 16-way min-merge of chunk partials, recompute the
//     winning group's 16 e-values BIT-IDENTICALLY -> first-occurrence argmin,
//     exact fp32 d2 for the selected index, EPS clamp, sqrt, sigma gather,
//     log+div, block-reduce to per-block partials.
//   final_reduce: sums 512 partials -> d_out.

#define BLK 256
#define TM 4
#define MTILE (BLK * TM)   // 1024 query points per block
#define NCHUNK 256         // target points staged in LDS per block
#define G 16               // argmin group size
#define FLT_BIG 3.402823466e38f

typedef _Float16 h2 __attribute__((ext_vector_type(2)));

// Monotone float -> uint transform (preserves total order incl. negatives).
__device__ __forceinline__ unsigned int f2mono(float f) {
    unsigned int u = __float_as_uint(f);
    return (u & 0x80000000u) ? ~u : (u | 0x80000000u);
}

__device__ __forceinline__ unsigned int packh2(float a, float b) {
    h2 v = { (_Float16)a, (_Float16)b };
    return __builtin_bit_cast(unsigned int, v);
}

// Must be used identically in nn_kernel and combine_kernel (bit-identical path).
__device__ __forceinline__ float edot(unsigned int txy_bits, h2 qxy, float acc) {
    return __builtin_amdgcn_fdot2(__builtin_bit_cast(h2, txy_bits), qxy, acc, false);
}

__global__ __launch_bounds__(BLK) void nn_kernel(
    const float* __restrict__ Q, const float* __restrict__ T,
    unsigned long long* __restrict__ pkeys, int Mq, int Nt, int totalQ)
{
    const int nChunks = Nt / NCHUNK;
    const int mTiles  = Mq / MTILE;
    int bid = blockIdx.x;
    int nc = bid % nChunks;
    int mt = (bid / nChunks) % mTiles;
    int b  = bid / (nChunks * mTiles);

    __shared__ __align__(16) unsigned int sXY[NCHUNK];
    __shared__ __align__(16) float        sZ[NCHUNK];
    __shared__ __align__(16) float        sW[NCHUNK];

    const float* Tb = T + (size_t)b * 3 * Nt;
    const int n0 = nc * NCHUNK;
    {   // BLK == NCHUNK: one target per thread. w-formula must match combine.
        int i = threadIdx.x;
        float x = Tb[0 * Nt + n0 + i];
        float y = Tb[1 * Nt + n0 + i];
        float z = Tb[2 * Nt + n0 + i];
        sXY[i] = packh2(x, y);
        sZ[i]  = z;
        sW[i]  = fmaf(x, x, fmaf(y, y, z * z));
    }
    __syncthreads();

    const float* Qb = Q + (size_t)b * 3 * Mq;
    const int mBase = mt * MTILE;

    h2 qxy[TM];
    float qz[TM], best[TM], gmin[TM];
    int bg[TM];
#pragma unroll
    for (int i = 0; i < TM; ++i) {
        int m = mBase + (int)threadIdx.x + i * BLK;   // coalesced
        float x = Qb[0 * Mq + m];
        float y = Qb[1 * Mq + m];
        float z = Qb[2 * Mq + m];
        qxy[i] = { (_Float16)(-2.0f * x), (_Float16)(-2.0f * y) };
        qz[i]  = -2.0f * z;
        best[i] = FLT_BIG;
        gmin[i] = FLT_BIG;
        bg[i] = 0;
    }

    const uint4*  sXY4 = (const uint4*)sXY;
    const float4* sZ4  = (const float4*)sZ;
    const float4* sW4  = (const float4*)sW;

    // Flat loop over 4-target subtiles; double-buffered register prefetch so
    // the next ds_reads' latency hides under this subtile's ~40 VALU insts.
    uint4  xy = sXY4[0];
    float4 zz = sZ4[0];
    float4 ww = sW4[0];
#pragma unroll 4
    for (int s = 0; s < NCHUNK / 4; ++s) {
        int nx = (s + 1) & (NCHUNK / 4 - 1);   // wraps to 0 on last; harmless
        uint4  xyn = sXY4[nx];
        float4 zzn = sZ4[nx];
        float4 wwn = sW4[nx];
#pragma unroll
        for (int i = 0; i < TM; ++i) {
            float e0 = edot(xy.x, qxy[i], fmaf(zz.x, qz[i], ww.x));
            float e1 = edot(xy.y, qxy[i], fmaf(zz.y, qz[i], ww.y));
            float e2 = edot(xy.z, qxy[i], fmaf(zz.z, qz[i], ww.z));
            float e3 = edot(xy.w, qxy[i], fmaf(zz.w, qz[i], ww.w));
            // 2x v_min3_f32
            gmin[i] = fminf(fminf(e0, e1), fminf(fminf(e2, e3), gmin[i]));
        }
        if ((s & 3) == 3) {                    // group boundary (G=16)
            int g = s >> 2;
#pragma unroll
            for (int i = 0; i < TM; ++i) {
                bool lt = gmin[i] < best[i];   // strict: earliest group on tie
                bg[i]   = lt ? g : bg[i];
                best[i] = lt ? gmin[i] : best[i];
                gmin[i] = FLT_BIG;
            }
        }
        xy = xyn; zz = zzn; ww = wwn;
    }

    // Disjoint per-chunk slots: plain coalesced stores, no init, no atomics.
    unsigned long long* dst = pkeys + (size_t)nc * totalQ + (size_t)b * Mq;
#pragma unroll
    for (int i = 0; i < TM; ++i) {
        int m = mBase + (int)threadIdx.x + i * BLK;
        dst[m] = ((unsigned long long)f2mono(best[i]) << 32) |
                 (unsigned long long)(unsigned int)(n0 / G + bg[i]);
    }
}

__global__ __launch_bounds__(BLK) void combine_kernel(
    const unsigned long long* __restrict__ pkeys, int nChunks, int totalQ,
    const float* __restrict__ Q, const float* __restrict__ T,
    const float* __restrict__ sigQ, const float* __restrict__ sigT,
    float* __restrict__ partials, float scale, int Mq, int Nt)
{
    int gid = blockIdx.x * BLK + (int)threadIdx.x;   // over B*Mq
    // Min-merge the per-chunk partial keys (16 coalesced u64 loads).
    unsigned long long key = 0xFFFFFFFFFFFFFFFFULL;
    for (int c = 0; c < nChunks; ++c) {
        unsigned long long k = pkeys[(size_t)c * totalQ + gid];
        key = (k < key) ? k : key;
    }
    int group = (int)(key & 0xFFFFFFFFu);
    int b = gid / Mq;
    int m = gid - b * Mq;

    const float* Qb = Q + (size_t)b * 3 * Mq;
    const float* Tb = T + (size_t)b * 3 * Nt;
    float x = Qb[0 * Mq + m], y = Qb[1 * Mq + m], z = Qb[2 * Mq + m];
    h2 qxy = { (_Float16)(-2.0f * x), (_Float16)(-2.0f * y) };
    float qz = -2.0f * z;
    float sq1 = fmaf(x, x, fmaf(y, y, z * z));

    // Scan winning group with the IDENTICAL f16 e-path used in nn_kernel ->
    // bit-identical values; strict < gives first-occurrence in-group argmin.
    int nbase = group * G;
    float beste = FLT_BIG;
    int bi = nbase;
#pragma unroll
    for (int k = 0; k < G; ++k) {
        int n = nbase + k;
        float tx = Tb[0 * Nt + n], ty = Tb[1 * Nt + n], tz = Tb[2 * Nt + n];
        float w = fmaf(tx, tx, fmaf(ty, ty, tz * tz));
        float e = edot(packh2(tx, ty), qxy, fmaf(tz, qz, w));
        bool lt = e < beste;
        bi    = lt ? n : bi;
        beste = lt ? e : beste;
    }

    // Exact fp32 distance of the selected index (f16 only perturbs near-tie
    // argmin choices; the evaluated distance is full precision).
    float tx = Tb[0 * Nt + bi], ty = Tb[1 * Nt + bi], tz = Tb[2 * Nt + bi];
    float w  = fmaf(tx, tx, fmaf(ty, ty, tz * tz));
    float cross = fmaf(x, tx, fmaf(y, ty, z * tz));
    float d2 = fmaxf(fmaf(-2.0f, cross, sq1 + w), 1e-12f);   // reference EPS

    float s = 0.5f * (sigQ[gid] + sigT[(size_t)b * Nt + bi]);
    float v = (logf(s) + sqrtf(d2) / s) * scale;

    __shared__ float red[BLK];
    red[threadIdx.x] = v;
    __syncthreads();
    for (int st = BLK / 2; st > 0; st >>= 1) {
        if ((int)threadIdx.x < st) red[threadIdx.x] += red[threadIdx.x + st];
        __syncthreads();
    }
    if (threadIdx.x == 0) partials[blockIdx.x] = red[0];
}

__global__ __launch_bounds__(512) void final_reduce(
    const float* __restrict__ partials, float* __restrict__ out, int n)
{
    __shared__ float red[512];
    int t = threadIdx.x;
    red[t] = (t < n) ? partials[t] : 0.0f;
    __syncthreads();
    for (int st = 256; st > 0; st >>= 1) {
        if (t < st) red[t] += red[t + st];
        __syncthreads();
    }
    if (t == 0) out[0] = red[0];
}

extern "C" void kernel_launch(void* const* d_in, const int* in_sizes, int n_in,
                              void* d_out, int out_size, void* d_ws, size_t ws_size,
                              hipStream_t stream) {
    const float* k1 = (const float*)d_in[0];   // (B,3,M)
    const float* k2 = (const float*)d_in[1];   // (B,3,N)
    const float* s1 = (const float*)d_in[2];   // (B,M)
    const float* s2 = (const float*)d_in[3];   // (B,N)
    float* out = (float*)d_out;

    const int B = 16, M = 4096, N = 4096;
    const int totalQ = B * M;                  // == B * N
    const int nChF = N / NCHUNK, nChB = M / NCHUNK;   // 16 each

    unsigned long long* pkF = (unsigned long long*)d_ws;             // 16*B*M
    unsigned long long* pkB = pkF + (size_t)nChF * totalQ;           // 16*B*N
    float* partials = (float*)(pkB + (size_t)nChB * totalQ);         // 512
    const int PF = (B * M) / BLK;                                    // 256
    const int PB = (B * N) / BLK;                                    // 256

    nn_kernel<<<B * (M / MTILE) * nChF, BLK, 0, stream>>>(k1, k2, pkF, M, N, totalQ);
    nn_kernel<<<B * (N / MTILE) * nChB, BLK, 0, stream>>>(k2, k1, pkB, N, M, totalQ);

    combine_kernel<<<PF, BLK, 0, stream>>>(pkF, nChF, totalQ, k1, k2, s1, s2,
                                           partials, 1.0f / (float)(B * M), M, N);
    combine_kernel<<<PB, BLK, 0, stream>>>(pkB, nChB, totalQ, k2, k1, s2, s1,
                                           partials + PF, 1.0f / (float)(B * N), N, M);

    final_reduce<<<1, 512, 0, stream>>>(partials, out, PF + PB);
}

// Round 6
// 50.629 us; speedup vs baseline: 1.4221x; 1.4221x over previous
//
#include <hip/hip_runtime.h>
#include <cstdint>

// ChamferLoss on MI355X — MFMA edition.
//   nn_mfma (1 launch, both directions): e[m,n] = ||t||^2 - 2 q.t computed as
//     a K=16 f16 GEMM via v_mfma_f32_32x32x16_f16 with hi/lo f16 splitting
//     (11 K-slots: 3 products per coordinate + w_hi + w_lo -> |err| ~2e-5,
//     fp32 accumulate). Each wave owns 64 queries (2 B-frags sharing each
//     A-frag ds_read) and scans a 2048-target half; per-lane fold of the 16
//     accumulator rows (min3 tree) + (best,group-of-32) tracking; cross-lane
//     merge lane^32; one coalesced u64 key store per query per half.
//     Any consistent K-slot permutation of A and B cancels in the dot
//     product, so only lane&31=row/col is assumed (matches verified C/D).
//   combine: 2-way key merge, 32-lane exact-fp32 rescan of the winning
//     group (first-occurrence argmin semantics, same formula that has given
//     absmax 0.0 since R2), EPS clamp, sqrt, sigma gather, loss partials.
//   final_reduce: sums 2048 partials -> d_out.

#define BLK 256
#define CHUNK 512          // targets staged in LDS per stage
#define NHALF 2048         // targets per block (half of N)
#define FLT_BIG 3.402823466e38f

typedef _Float16 f16x8 __attribute__((ext_vector_type(8)));
typedef float    f32x16 __attribute__((ext_vector_type(16)));

__device__ __forceinline__ unsigned int f2mono(float f) {
    unsigned int u = __float_as_uint(f);
    return (u & 0x80000000u) ? ~u : (u | 0x80000000u);
}

__device__ __forceinline__ void fsplit(float v, _Float16& h, _Float16& l) {
    h = (_Float16)v;
    l = (_Float16)(v - (float)h);
}

__device__ __forceinline__ unsigned long long shflxor_u64(
    unsigned long long v, int mask, int width) {
    unsigned lo = (unsigned)v, hi = (unsigned)(v >> 32);
    lo = __shfl_xor(lo, mask, width);
    hi = __shfl_xor(hi, mask, width);
    return ((unsigned long long)hi << 32) | lo;
}

// Min-fold 16 accumulator values (min3-fusable tree) + (best, group) update.
__device__ __forceinline__ void fold(const f32x16& c, float& best, int& bg, int g) {
    float t0 = fminf(fminf(c[0], c[1]), c[2]);
    float t1 = fminf(fminf(c[3], c[4]), c[5]);
    float t2 = fminf(fminf(c[6], c[7]), c[8]);
    float t3 = fminf(fminf(c[9], c[10]), c[11]);
    float t4 = fminf(fminf(c[12], c[13]), c[14]);
    float v  = fminf(fminf(fminf(t0, t1), t2), fminf(fminf(t3, t4), c[15]));
    bool lt = v < best;              // strict: earliest group on tie
    bg   = lt ? g : bg;
    best = lt ? v : best;
}

__global__ __launch_bounds__(BLK) void nn_mfma(
    const float* __restrict__ K1, const float* __restrict__ K2,
    unsigned long long* __restrict__ pkeys)
{
    // grid 1024: half | mtile(16) | b(16) | dir
    int bid  = blockIdx.x;
    int half = bid & 1;
    int mt   = (bid >> 1) & 15;
    int b    = (bid >> 5) & 15;
    int dir  = bid >> 9;

    const float* Qp = dir ? K2 : K1;
    const float* Tp = dir ? K1 : K2;
    const float* Qb = Qp + (size_t)b * 3 * 4096;
    const float* Tb = Tp + (size_t)b * 3 * 4096;

    __shared__ f16x8 sA[2][CHUNK / 32][64];   // [buf][tile][lane-slot] 32 KB

    const int tid  = threadIdx.x;
    const int l    = tid & 63;
    const int wid  = tid >> 6;
    const int c31  = l & 31;
    const int lh   = l >> 5;

    // ---- per-lane query B-frags (built once; lane&31 = column = query) ----
    const int mBase = mt * 256 + wid * 64;
    f16x8 bq[2];
#pragma unroll
    for (int qs = 0; qs < 2; ++qs) {
        int m = mBase + qs * 32 + c31;
        float x = Qb[0 * 4096 + m], y = Qb[1 * 4096 + m], z = Qb[2 * 4096 + m];
        _Float16 Xh, Xl, Yh, Yl, Zh, Zl;
        fsplit(-2.0f * x, Xh, Xl);
        fsplit(-2.0f * y, Yh, Yl);
        fsplit(-2.0f * z, Zh, Zl);
        f16x8 v;
        const _Float16 one = (_Float16)1.0f, zr = (_Float16)0.0f;
        v[0] = lh ? Zh  : Xh;  v[1] = lh ? one : Xl;
        v[2] = lh ? one : Xh;  v[3] = lh ? zr  : Yh;
        v[4] = lh ? zr  : Yl;  v[5] = lh ? zr  : Yh;
        v[6] = lh ? zr  : Zh;  v[7] = lh ? zr  : Zl;
        bq[qs] = v;
    }

    const f32x16 zero = {};
    float best0 = FLT_BIG, best1 = FLT_BIG;
    int   bg0 = 0, bg1 = 0;

    const int nBase = half * NHALF;
    float tx[2], ty[2], tz[2];

    // ---- prologue: load + stage chunk 0 ----
#pragma unroll
    for (int j = 0; j < 2; ++j) {
        int n = nBase + tid + j * 256;
        tx[j] = Tb[0 * 4096 + n]; ty[j] = Tb[1 * 4096 + n]; tz[j] = Tb[2 * 4096 + n];
    }
#pragma unroll
    for (int j = 0; j < 2; ++j) {
        _Float16 xh, xl, yh, yl, zh, zl, wh, wl;
        fsplit(tx[j], xh, xl); fsplit(ty[j], yh, yl); fsplit(tz[j], zh, zl);
        float w = fmaf(tx[j], tx[j], fmaf(ty[j], ty[j], tz[j] * tz[j]));
        fsplit(w, wh, wl);
        const _Float16 zr = (_Float16)0.0f;
        f16x8 h0 = {xh, xl, xh, yh, yl, yh, zh, zl};      // B-side k0-7 mirror
        f16x8 h1 = {zl, wh, wl, zr, zr, zr, zr, zr};
        // A-side ordering must pair with B per K slot:
        // k: t * q -> {xh*Xh, xh*Xl?...}. Use A = {xh,xh,xl,yh,yh,yl,zh,zh} etc.
        f16x8 a0 = {xh, xh, xl, yh, yh, yl, zh, zh};
        f16x8 a1 = {zl, wh, wl, zr, zr, zr, zr, zr};
        (void)h0; (void)h1;
        int nc = tid + j * 256;
        sA[0][nc >> 5][(nc & 31)]      = a0;
        sA[0][nc >> 5][32 + (nc & 31)] = a1;
    }
    __syncthreads();

    // ---- main loop over 4 chunks, double-buffered ----
    for (int c = 0; c < 4; ++c) {
        int p = c & 1;
        if (c < 3) {
#pragma unroll
            for (int j = 0; j < 2; ++j) {
                int n = nBase + (c + 1) * CHUNK + tid + j * 256;
                tx[j] = Tb[0 * 4096 + n]; ty[j] = Tb[1 * 4096 + n]; tz[j] = Tb[2 * 4096 + n];
            }
        }
        int gB = half * 64 + c * 16;
#pragma unroll 4
        for (int t = 0; t < 16; ++t) {
            f16x8 a = sA[p][t][l];                       // ds_read_b128
            f32x16 c0 = __builtin_amdgcn_mfma_f32_32x32x16_f16(a, bq[0], zero, 0, 0, 0);
            f32x16 c1 = __builtin_amdgcn_mfma_f32_32x32x16_f16(a, bq[1], zero, 0, 0, 0);
            fold(c0, best0, bg0, gB + t);
            fold(c1, best1, bg1, gB + t);
        }
        if (c < 3) {
#pragma unroll
            for (int j = 0; j < 2; ++j) {
                _Float16 xh, xl, yh, yl, zh, zl, wh, wl;
                fsplit(tx[j], xh, xl); fsplit(ty[j], yh, yl); fsplit(tz[j], zh, zl);
                float w = fmaf(tx[j], tx[j], fmaf(ty[j], ty[j], tz[j] * tz[j]));
                fsplit(w, wh, wl);
                const _Float16 zr = (_Float16)0.0f;
                f16x8 a0 = {xh, xh, xl, yh, yh, yl, zh, zh};
                f16x8 a1 = {zl, wh, wl, zr, zr, zr, zr, zr};
                int nc = tid + j * 256;
                sA[p ^ 1][nc >> 5][(nc & 31)]      = a0;
                sA[p ^ 1][nc >> 5][32 + (nc & 31)] = a1;
            }
        }
        __syncthreads();
    }

    // ---- merge lane^32 (same query column, other row-half) and store ----
    unsigned long long k0 = ((unsigned long long)f2mono(best0) << 32) | (unsigned)bg0;
    unsigned long long k1 = ((unsigned long long)f2mono(best1) << 32) | (unsigned)bg1;
    unsigned long long m0 = shflxor_u64(k0, 32, 64);
    unsigned long long m1 = shflxor_u64(k1, 32, 64);
    k0 = (m0 < k0) ? m0 : k0;
    k1 = (m1 < k1) ? m1 : k1;
    unsigned long long kf = (lh == 0) ? k0 : k1;   // lane l -> query mBase + l
    pkeys[((size_t)(dir * 2 + half)) * 65536 + (size_t)b * 4096 + mBase + l] = kf;
}

__global__ __launch_bounds__(BLK) void combine_kernel(
    const unsigned long long* __restrict__ pkeys,
    const float* __restrict__ K1, const float* __restrict__ K2,
    const float* __restrict__ s1, const float* __restrict__ s2,
    float* __restrict__ partials)
{
    // 2048 blocks; each 32-lane group handles 8 queries; 64 queries/block.
    const int tid = threadIdx.x;
    const int grp = tid >> 5, la = tid & 31;
    const int dir = (int)(blockIdx.x >> 10);           // uniform per block
    const float* Qp = dir ? K2 : K1;
    const float* Tp = dir ? K1 : K2;
    const float* sQ = dir ? s2 : s1;
    const float* sT = dir ? s1 : s2;
    const float scale = 1.0f / 65536.0f;

    float acc = 0.0f;
#pragma unroll
    for (int j = 0; j < 8; ++j) {
        int q  = (int)blockIdx.x * 64 + grp * 8 + j;   // 0..131071
        int qq = q & 65535;
        int b  = qq >> 12, m = qq & 4095;
        unsigned long long kA = pkeys[(size_t)(dir * 2 + 0) * 65536 + qq];
        unsigned long long kB = pkeys[(size_t)(dir * 2 + 1) * 65536 + qq];
        unsigned long long key = (kA < kB) ? kA : kB;
        int g = (int)(key & 0xFFFFFFFFu);

        const float* Qb = Qp + (size_t)b * 3 * 4096;
        const float* Tb = Tp + (size_t)b * 3 * 4096;
        float x = Qb[m], y = Qb[4096 + m], z = Qb[2 * 4096 + m];
        float X = -2.0f * x, Y = -2.0f * y, Z = -2.0f * z;
        float sq1 = fmaf(x, x, fmaf(y, y, z * z));

        int n = g * 32 + la;                           // coalesced 128B segment
        float txv = Tb[n], tyv = Tb[4096 + n], tzv = Tb[2 * 4096 + n];
        float w = fmaf(txv, txv, fmaf(tyv, tyv, tzv * tzv));
        float e = fmaf(txv, X, fmaf(tyv, Y, fmaf(tzv, Z, w)));   // exact fp32

        // 32-lane argmin, first-occurrence: key = mono(e)<<32 | n.
        unsigned long long rk = ((unsigned long long)f2mono(e) << 32) | (unsigned)n;
#pragma unroll
        for (int sft = 1; sft < 32; sft <<= 1) {
            unsigned long long o = shflxor_u64(rk, sft, 32);
            rk = (o < rk) ? o : rk;
        }
        int bi = (int)(rk & 0xFFFFFFFFu);
        float emin = __uint_as_float((unsigned)(rk >> 32));
        emin = (emin >= 0.f || true)
             ? __uint_as_float(((rk >> 32) & 0x80000000ULL) ? (unsigned)((rk >> 32) ^ 0x80000000ULL)
                                                            : ~(unsigned)(rk >> 32))
             : emin;   // mono^-1

        float d2 = fmaxf(sq1 + emin, 1e-12f);          // reference EPS clamp
        float s = 0.5f * (sQ[qq] + sT[b * 4096 + bi]);
        float v = (logf(s) + sqrtf(d2) / s) * scale;
        if (la == 0) acc += v;
    }

    __shared__ float red[BLK];
    red[tid] = acc;
    __syncthreads();
    for (int st = BLK / 2; st > 0; st >>= 1) {
        if (tid < st) red[tid] += red[tid + st];
        __syncthreads();
    }
    if (tid == 0) partials[blockIdx.x] = red[0];
}

__global__ __launch_bounds__(256) void final_reduce(
    const float* __restrict__ partials, float* __restrict__ out, int n)
{
    __shared__ float red[256];
    int t = threadIdx.x;
    float a = 0.0f;
    for (int i = t; i < n; i += 256) a += partials[i];
    red[t] = a;
    __syncthreads();
    for (int st = 128; st > 0; st >>= 1) {
        if (t < st) red[t] += red[t + st];
        __syncthreads();
    }
    if (t == 0) out[0] = red[0];
}

extern "C" void kernel_launch(void* const* d_in, const int* in_sizes, int n_in,
                              void* d_out, int out_size, void* d_ws, size_t ws_size,
                              hipStream_t stream) {
    const float* k1 = (const float*)d_in[0];   // (B,3,M)
    const float* k2 = (const float*)d_in[1];   // (B,3,N)
    const float* s1 = (const float*)d_in[2];   // (B,M)
    const float* s2 = (const float*)d_in[3];   // (B,N)
    float* out = (float*)d_out;

    unsigned long long* pkeys = (unsigned long long*)d_ws;   // 4 * 65536 keys
    float* partials = (float*)(pkeys + (size_t)4 * 65536);   // 2048 floats

    nn_mfma<<<1024, BLK, 0, stream>>>(k1, k2, pkeys);
    combine_kernel<<<2048, BLK, 0, stream>>>(pkeys, k1, k2, s1, s2, partials);
    final_reduce<<<1, 256, 0, stream>>>(partials, out, 2048);
}

// Round 7
// 45.421 us; speedup vs baseline: 1.5851x; 1.1146x over previous
//
#include <hip/hip_runtime.h>
#include <cstdint>

// ChamferLoss on MI355X — MFMA edition v2.
//   nn_mfma (1 launch, both directions): e[m,n] = ||t||^2 - 2 q.t as K=16 f16
//     GEMM via v_mfma_f32_32x32x16_f16, hi/lo f16 splitting (11 K-slots,
//     fp32 accumulate, |err|~2e-5). Per wave: 64 queries (2 B-frags / A-frag
//     ds_read). Grid 2048: each block scans a QUARTER (1024 targets) ->
//     8 blocks/CU for latency hiding. Fold of 16 acc rows via explicit
//     v_min3_f32 asm (8 ops) + (best,group-of-32); lane^32 merge; one
//     coalesced u64 key store per query per quarter.
//   combine: 4-way key merge, per-thread exact-fp32 scan of the winning
//     32-group (float4 loads, strict < = first-occurrence argmin), EPS clamp,
//     sqrt, sigma gather, loss partials (512 blocks).
//   final_reduce: sums 512 partials -> d_out.

#define BLK 256
#define CHUNK 512          // targets staged in LDS per stage
#define NQTR 1024          // targets per block (quarter of N)
#define FLT_BIG 3.402823466e38f

typedef _Float16 f16x8 __attribute__((ext_vector_type(8)));
typedef float    f32x16 __attribute__((ext_vector_type(16)));

__device__ __forceinline__ unsigned int f2mono(float f) {
    unsigned int u = __float_as_uint(f);
    return (u & 0x80000000u) ? ~u : (u | 0x80000000u);
}

__device__ __forceinline__ void fsplit(float v, _Float16& h, _Float16& l) {
    h = (_Float16)v;
    l = (_Float16)(v - (float)h);
}

__device__ __forceinline__ float min3f(float a, float b, float c) {
    float d;
    asm("v_min3_f32 %0, %1, %2, %3" : "=v"(d) : "v"(a), "v"(b), "v"(c));
    return d;
}

__device__ __forceinline__ unsigned long long shflxor_u64_32(unsigned long long v) {
    unsigned lo = (unsigned)v, hi = (unsigned)(v >> 32);
    lo = __shfl_xor(lo, 32, 64);
    hi = __shfl_xor(hi, 32, 64);
    return ((unsigned long long)hi << 32) | lo;
}

// Min-fold 16 accumulator values (guaranteed min3 tree) + (best,group) update.
__device__ __forceinline__ void fold(const f32x16& c, float& best, int& bg, int g) {
    float t0 = min3f(c[0], c[1], c[2]);
    float t1 = min3f(c[3], c[4], c[5]);
    float t2 = min3f(c[6], c[7], c[8]);
    float t3 = min3f(c[9], c[10], c[11]);
    float t4 = min3f(c[12], c[13], c[14]);
    float u0 = min3f(t0, t1, c[15]);
    float u1 = min3f(t2, t3, t4);
    float v  = fminf(u0, u1);
    bool lt = v < best;              // strict: earliest group on tie
    bg   = lt ? g : bg;
    best = lt ? v : best;
}

__global__ __launch_bounds__(BLK) void nn_mfma(
    const float* __restrict__ K1, const float* __restrict__ K2,
    unsigned long long* __restrict__ pkeys)
{
    // grid 2048: qtr(4) | mtile(16) | b(16) | dir(2)
    int bid = blockIdx.x;
    int qtr = bid & 3;
    int mt  = (bid >> 2) & 15;
    int b   = (bid >> 6) & 15;
    int dir = bid >> 10;

    const float* Qp = dir ? K2 : K1;
    const float* Tp = dir ? K1 : K2;
    const float* Qb = Qp + (size_t)b * 3 * 4096;
    const float* Tb = Tp + (size_t)b * 3 * 4096;

    __shared__ f16x8 sA[2][CHUNK / 32][64];   // 32 KB

    const int tid = threadIdx.x;
    const int l   = tid & 63;
    const int wid = tid >> 6;
    const int c31 = l & 31;
    const int lh  = l >> 5;

    // ---- per-lane query B-frags (lane&31 = column = query) ----
    const int mBase = mt * 256 + wid * 64;
    f16x8 bq[2];
#pragma unroll
    for (int qs = 0; qs < 2; ++qs) {
        int m = mBase + qs * 32 + c31;
        float x = Qb[0 * 4096 + m], y = Qb[1 * 4096 + m], z = Qb[2 * 4096 + m];
        _Float16 Xh, Xl, Yh, Yl, Zh, Zl;
        fsplit(-2.0f * x, Xh, Xl);
        fsplit(-2.0f * y, Yh, Yl);
        fsplit(-2.0f * z, Zh, Zl);
        f16x8 v;
        const _Float16 one = (_Float16)1.0f, zr = (_Float16)0.0f;
        v[0] = lh ? Zh  : Xh;  v[1] = lh ? one : Xl;
        v[2] = lh ? one : Xh;  v[3] = lh ? zr  : Yh;
        v[4] = lh ? zr  : Yl;  v[5] = lh ? zr  : Yh;
        v[6] = lh ? zr  : Zh;  v[7] = lh ? zr  : Zl;
        bq[qs] = v;
    }

    const f32x16 zero = {};
    float best0 = FLT_BIG, best1 = FLT_BIG;
    int   bg0 = 0, bg1 = 0;

    const int nBase = qtr * NQTR;
    float tx[2], ty[2], tz[2];

    // ---- prologue: load + stage chunk 0 ----
#pragma unroll
    for (int j = 0; j < 2; ++j) {
        int n = nBase + tid + j * 256;
        tx[j] = Tb[0 * 4096 + n]; ty[j] = Tb[1 * 4096 + n]; tz[j] = Tb[2 * 4096 + n];
    }
#pragma unroll
    for (int j = 0; j < 2; ++j) {
        _Float16 xh, xl, yh, yl, zh, zl, wh, wl;
        fsplit(tx[j], xh, xl); fsplit(ty[j], yh, yl); fsplit(tz[j], zh, zl);
        float w = fmaf(tx[j], tx[j], fmaf(ty[j], ty[j], tz[j] * tz[j]));
        fsplit(w, wh, wl);
        const _Float16 zr = (_Float16)0.0f;
        f16x8 a0 = {xh, xh, xl, yh, yh, yl, zh, zh};
        f16x8 a1 = {zl, wh, wl, zr, zr, zr, zr, zr};
        int nc = tid + j * 256;
        sA[0][nc >> 5][(nc & 31)]      = a0;
        sA[0][nc >> 5][32 + (nc & 31)] = a1;
    }
    __syncthreads();

    // ---- main loop over 2 chunks, double-buffered ----
    for (int c = 0; c < 2; ++c) {
        int p = c & 1;
        if (c < 1) {
#pragma unroll
            for (int j = 0; j < 2; ++j) {
                int n = nBase + CHUNK + tid + j * 256;
                tx[j] = Tb[0 * 4096 + n]; ty[j] = Tb[1 * 4096 + n]; tz[j] = Tb[2 * 4096 + n];
            }
        }
        int gB = qtr * 32 + c * 16;              // global group-of-32 base
#pragma unroll 4
        for (int t = 0; t < 16; ++t) {
            f16x8 a = sA[p][t][l];               // ds_read_b128
            f32x16 c0 = __builtin_amdgcn_mfma_f32_32x32x16_f16(a, bq[0], zero, 0, 0, 0);
            f32x16 c1 = __builtin_amdgcn_mfma_f32_32x32x16_f16(a, bq[1], zero, 0, 0, 0);
            fold(c0, best0, bg0, gB + t);
            fold(c1, best1, bg1, gB + t);
        }
        if (c < 1) {
#pragma unroll
            for (int j = 0; j < 2; ++j) {
                _Float16 xh, xl, yh, yl, zh, zl, wh, wl;
                fsplit(tx[j], xh, xl); fsplit(ty[j], yh, yl); fsplit(tz[j], zh, zl);
                float w = fmaf(tx[j], tx[j], fmaf(ty[j], ty[j], tz[j] * tz[j]));
                fsplit(w, wh, wl);
                const _Float16 zr = (_Float16)0.0f;
                f16x8 a0 = {xh, xh, xl, yh, yh, yl, zh, zh};
                f16x8 a1 = {zl, wh, wl, zr, zr, zr, zr, zr};
                int nc = tid + j * 256;
                sA[p ^ 1][nc >> 5][(nc & 31)]      = a0;
                sA[p ^ 1][nc >> 5][32 + (nc & 31)] = a1;
            }
        }
        __syncthreads();
    }

    // ---- merge lane^32 (same query column, other row-half) and store ----
    unsigned long long k0 = ((unsigned long long)f2mono(best0) << 32) | (unsigned)bg0;
    unsigned long long k1 = ((unsigned long long)f2mono(best1) << 32) | (unsigned)bg1;
    unsigned long long m0 = shflxor_u64_32(k0);
    unsigned long long m1 = shflxor_u64_32(k1);
    k0 = (m0 < k0) ? m0 : k0;
    k1 = (m1 < k1) ? m1 : k1;
    unsigned long long kf = (lh == 0) ? k0 : k1;   // lane l -> query mBase + l
    pkeys[((size_t)(dir * 4 + qtr)) * 65536 + (size_t)b * 4096 + mBase + l] = kf;
}

__global__ __launch_bounds__(BLK) void combine_kernel(
    const unsigned long long* __restrict__ pkeys,
    const float* __restrict__ K1, const float* __restrict__ K2,
    const float* __restrict__ s1, const float* __restrict__ s2,
    float* __restrict__ partials)
{
    int gid = blockIdx.x * BLK + (int)threadIdx.x;   // 0..131071
    int dir = gid >> 16;
    int qq  = gid & 65535;
    int b   = qq >> 12, m = qq & 4095;

    const float* Qp = dir ? K2 : K1;
    const float* Tp = dir ? K1 : K2;
    const float* sQ = dir ? s2 : s1;
    const float* sT = dir ? s1 : s2;
    const float scale = 1.0f / 65536.0f;

    // 4-way merge of quarter keys (coalesced u64 loads).
    unsigned long long key = 0xFFFFFFFFFFFFFFFFULL;
#pragma unroll
    for (int q = 0; q < 4; ++q) {
        unsigned long long k = pkeys[(size_t)(dir * 4 + q) * 65536 + qq];
        key = (k < key) ? k : key;
    }
    int g = (int)(key & 0xFFFFFFFFu);

    const float* Qb = Qp + (size_t)b * 3 * 4096;
    const float* Tb = Tp + (size_t)b * 3 * 4096;
    float x = Qb[m], y = Qb[4096 + m], z = Qb[2 * 4096 + m];
    float X = -2.0f * x, Y = -2.0f * y, Z = -2.0f * z;
    float sq1 = fmaf(x, x, fmaf(y, y, z * z));

    // Exact-fp32 serial scan of the winning 32-group; strict < gives
    // first-occurrence argmin. n0 is 128B-aligned -> float4 loads.
    int n0 = g * 32;
    const float4* Tx4 = (const float4*)(Tb + n0);
    const float4* Ty4 = (const float4*)(Tb + 4096 + n0);
    const float4* Tz4 = (const float4*)(Tb + 2 * 4096 + n0);
    float beste = FLT_BIG;
    int bi = n0;
#pragma unroll
    for (int j = 0; j < 8; ++j) {
        float4 xv = Tx4[j], yv = Ty4[j], zv = Tz4[j];
#pragma unroll
        for (int k = 0; k < 4; ++k) {
            float txv = ((const float*)&xv)[k];
            float tyv = ((const float*)&yv)[k];
            float tzv = ((const float*)&zv)[k];
            float w = fmaf(txv, txv, fmaf(tyv, tyv, tzv * tzv));
            float e = fmaf(txv, X, fmaf(tyv, Y, fmaf(tzv, Z, w)));
            bool lt = e < beste;
            bi    = lt ? (n0 + j * 4 + k) : bi;
            beste = lt ? e : beste;
        }
    }

    float d2 = fmaxf(sq1 + beste, 1e-12f);           // reference EPS clamp
    float s = 0.5f * (sQ[qq] + sT[b * 4096 + bi]);
    float v = (logf(s) + sqrtf(d2) / s) * scale;

    __shared__ float red[BLK];
    red[threadIdx.x] = v;
    __syncthreads();
    for (int st = BLK / 2; st > 0; st >>= 1) {
        if ((int)threadIdx.x < st) red[threadIdx.x] += red[threadIdx.x + st];
        __syncthreads();
    }
    if (threadIdx.x == 0) partials[blockIdx.x] = red[0];
}

__global__ __launch_bounds__(256) void final_reduce(
    const float* __restrict__ partials, float* __restrict__ out, int n)
{
    __shared__ float red[256];
    int t = threadIdx.x;
    float a = 0.0f;
    for (int i = t; i < n; i += 256) a += partials[i];
    red[t] = a;
    __syncthreads();
    for (int st = 128; st > 0; st >>= 1) {
        if (t < st) red[t] += red[t + st];
        __syncthreads();
    }
    if (t == 0) out[0] = red[0];
}

extern "C" void kernel_launch(void* const* d_in, const int* in_sizes, int n_in,
                              void* d_out, int out_size, void* d_ws, size_t ws_size,
                              hipStream_t stream) {
    const float* k1 = (const float*)d_in[0];   // (B,3,M)
    const float* k2 = (const float*)d_in[1];   // (B,3,N)
    const float* s1 = (const float*)d_in[2];   // (B,M)
    const float* s2 = (const float*)d_in[3];   // (B,N)
    float* out = (float*)d_out;

    unsigned long long* pkeys = (unsigned long long*)d_ws;   // 8 * 65536 keys
    float* partials = (float*)(pkeys + (size_t)8 * 65536);   // 512 floats

    nn_mfma<<<2048, BLK, 0, stream>>>(k1, k2, pkeys);
    combine_kernel<<<512, BLK, 0, stream>>>(pkeys, k1, k2, s1, s2, partials);
    final_reduce<<<1, 256, 0, stream>>>(partials, out, 512);
}